// Round 4
// baseline (35.784 us; speedup 1.0000x reference)
//
#include <hip/hip_runtime.h>
#include <math.h>

// B=8, L=4096, D=64, M=64, masked=1 (fixed by setup_inputs)
#define BB 8
#define LL 4096
#define DD 64
#define SS 64
#define NCHUNK 64
#define STATE 4160  // 64x64 KV^T rows (d-major) + 64 N values

typedef __attribute__((ext_vector_type(8))) short s16x8;
typedef __attribute__((ext_vector_type(8))) unsigned short u16x8;
typedef __attribute__((ext_vector_type(4))) float f32x4;

#define MFMA(a, b, c) __builtin_amdgcn_mfma_f32_16x16x32_bf16((a), (b), (c), 0, 0, 0)

static __device__ __forceinline__ unsigned short f2bf(float x) {
  unsigned int u = __builtin_bit_cast(unsigned int, x);
  u += 0x7FFFu + ((u >> 16) & 1u);
  return (unsigned short)(u >> 16);
}
static __device__ __forceinline__ float bf2f(unsigned short h) {
  unsigned int u = ((unsigned int)h) << 16;
  return __builtin_bit_cast(float, u);
}

// Fragment load from an operand tile stored row-major (64 cols of bf16 per row)
// with XOR swizzle: element (r, k) lives at ushort index r*64 + (k ^ ((r&7)<<3)).
static __device__ __forceinline__ s16x8 ld_frag(const unsigned short* base, int row0, int ks) {
  const int lane = threadIdx.x & 63;
  const int r = row0 + (lane & 15);
  const int idx = r * 64 + ((ks * 32 + ((lane & 48) >> 1)) ^ ((r & 7) << 3));
  return *(const s16x8*)(base + idx);
}

// Stage a 64x64 f32 global tile into hi/lo bf16 LDS tiles (swizzled).
static __device__ __forceinline__ void stage_hl(unsigned short* __restrict__ Sh,
                                                unsigned short* __restrict__ Sl,
                                                const float* __restrict__ src, int tid) {
#pragma unroll
  for (int it = 0; it < 2; ++it) {
    const int g = tid + it * 256;
    const int row = g >> 3;
    const int c0 = (g & 7) * 8;
    const float4 x0 = *(const float4*)(src + row * 64 + c0);
    const float4 x1 = *(const float4*)(src + row * 64 + c0 + 4);
    const float xs[8] = {x0.x, x0.y, x0.z, x0.w, x1.x, x1.y, x1.z, x1.w};
    u16x8 h, l;
#pragma unroll
    for (int k = 0; k < 8; ++k) {
      const unsigned short hh = f2bf(xs[k]);
      h[k] = hh;
      l[k] = f2bf(xs[k] - bf2f(hh));
    }
    const int idx = row * 64 + (c0 ^ ((row & 7) << 3));
    *(u16x8*)(Sh + idx) = h;
    *(u16x8*)(Sl + idx) = l;
  }
}

// 3-term split-precision logits: acc += Ah*Bh + Ah*Bl + Al*Bh  (wave row-tile w)
static __device__ __forceinline__ void logits3(const unsigned short* Ah_, const unsigned short* Al_,
                                               const unsigned short* Bh_, const unsigned short* Bl_,
                                               int w, f32x4 acc[4]) {
  s16x8 ah[2], al[2];
#pragma unroll
  for (int ks = 0; ks < 2; ++ks) {
    ah[ks] = ld_frag(Ah_, w * 16, ks);
    al[ks] = ld_frag(Al_, w * 16, ks);
  }
#pragma unroll
  for (int ct = 0; ct < 4; ++ct) {
#pragma unroll
    for (int ks = 0; ks < 2; ++ks) {
      const s16x8 bh = ld_frag(Bh_, ct * 16, ks);
      const s16x8 bl = ld_frag(Bl_, ct * 16, ks);
      acc[ct] = MFMA(ah[ks], bh, acc[ct]);
      acc[ct] = MFMA(ah[ks], bl, acc[ct]);
      acc[ct] = MFMA(al[ks], bh, acc[ct]);
    }
  }
}

// phi = exp(logit)*sc; store row-major [t][m] (swizzled).
static __device__ __forceinline__ void phi_store_row(unsigned short* dst, const f32x4* acc,
                                                     const float* sc, int w) {
  const int lane = threadIdx.x & 63;
#pragma unroll
  for (int ri = 0; ri < 4; ++ri) {
    const int t = w * 16 + ((lane & 48) >> 2) + ri;
#pragma unroll
    for (int ct = 0; ct < 4; ++ct) {
      const int m = ct * 16 + (lane & 15);
      dst[t * 64 + (m ^ ((t & 7) << 3))] = f2bf(__expf(acc[ct][ri]) * sc[ri]);
    }
  }
}

// phi stored transposed [m][t] (swizzled) — B-operand layout for KV chunk sums.
static __device__ __forceinline__ void phi_store_col(unsigned short* dst, const f32x4* acc,
                                                     const float* sc, int w) {
  const int lane = threadIdx.x & 63;
#pragma unroll
  for (int ri = 0; ri < 4; ++ri) {
    const int t = w * 16 + ((lane & 48) >> 2) + ri;
#pragma unroll
    for (int ct = 0; ct < 4; ++ct) {
      const int m = ct * 16 + (lane & 15);
      dst[m * 64 + (t ^ ((m & 7) << 3))] = f2bf(__expf(acc[ct][ri]) * sc[ri]);
    }
  }
}

// Stage one 32-row half of V (f32) into scratch.
static __device__ __forceinline__ void stage_vhalf(float* __restrict__ F, const float* __restrict__ src,
                                                   int tid) {
#pragma unroll
  for (int it = 0; it < 2; ++it) {
    const int g = tid + it * 256;
    const int row = g >> 4;
    const int col = (g & 15) * 4;
    *(float4*)(F + row * 64 + col) = *(const float4*)(src + row * 64 + col);
  }
}

// Stage full 64x64 V f32 tile.
static __device__ __forceinline__ void stage_vfull(float* __restrict__ F, const float* __restrict__ src,
                                                   int tid) {
#pragma unroll
  for (int it = 0; it < 4; ++it) {
    const int g = tid + it * 256;
    const int row = g >> 4;
    const int col = (g & 15) * 4;
    *(float4*)(F + row * 64 + col) = *(const float4*)(src + row * 64 + col);
  }
}

// Transpose 32 rows of f32 scratch into VT hi/lo bf16 tiles: VT[d][t] (swizzled).
static __device__ __forceinline__ void vtrans_half(unsigned short* __restrict__ Gh,
                                                   unsigned short* __restrict__ Hl,
                                                   const float* __restrict__ F, int tid, int half) {
  const int d = tid & 63;
  const int tb = (tid >> 6) * 8;
  float v[8];
#pragma unroll
  for (int k = 0; k < 8; ++k) v[k] = F[(tb + k) * 64 + d];
  u16x8 hh, ll;
#pragma unroll
  for (int k = 0; k < 8; ++k) {
    const unsigned short h = f2bf(v[k]);
    hh[k] = h;
    ll[k] = f2bf(v[k] - bf2f(h));
  }
  const int idx = d * 64 + ((half * 32 + tb) ^ ((d & 7) << 3));
  *(u16x8*)(Gh + idx) = hh;
  *(u16x8*)(Hl + idx) = ll;
}

// ---------------- K1: per-timestep scales ----------------
__global__ __launch_bounds__(256) void k_scales(const float* __restrict__ Q,
                                                const float* __restrict__ K,
                                                float* __restrict__ ws) {
  const int t = blockIdx.x * 4 + (threadIdx.x >> 6);
  const int lane = threadIdx.x & 63;
  const int b = lane >> 3;
  const int d0 = (lane & 7) * 8;
  const size_t base = (size_t)b * (LL * DD) + (size_t)t * DD + d0;
  float sq = 0.f, sk = 0.f;
#pragma unroll
  for (int k = 0; k < 8; ++k) {
    const float q = Q[base + k]; sq += q * q;
    const float kk = K[base + k]; sk += kk * kk;
  }
#pragma unroll
  for (int off = 32; off; off >>= 1) {
    sq += __shfl_xor(sq, off);
    sk += __shfl_xor(sk, off);
  }
  if (lane == 0) {
    ws[t]      = expf(-0.5f * sqrtf(sq));
    ws[LL + t] = expf(-0.5f * sqrtf(sk));
  }
}

// ---------------- K2: phi(Q,K) + per-chunk sums ----------------
// Writes quantized phiQ/phiK LDS images (swizzled [t][m] bf16) to ws for reuse by k_out,
// plus chunk state: KVT[d][m] = V^T phiK, N[m] = colsum(phiK).
__global__ __launch_bounds__(256) void k_phi_sums(const float* __restrict__ Qg,
                                                  const float* __restrict__ Kg,
                                                  const float* __restrict__ Vg,
                                                  const float* __restrict__ proj,
                                                  const float* __restrict__ ws,
                                                  float* __restrict__ states,
                                                  unsigned short* __restrict__ phiQg,
                                                  unsigned short* __restrict__ phiKg) {
  __shared__ unsigned short P0[4096], P1[4096];  // proj hi/lo
  __shared__ unsigned short X0[4096], X1[4096];  // Q hi/lo -> X0 becomes phiQ row image
  __shared__ unsigned short Y0[4096], Y1[4096];  // K hi/lo -> VT hi/lo
  __shared__ unsigned short PHIr[4096];          // phiK row image [t][m]
  __shared__ unsigned short PHIc[4096];          // phiK col image [m][t]
  __shared__ float F[2048];                      // V half f32 scratch
  const int tid = threadIdx.x;
  const int lane = tid & 63;
  const int w = tid >> 6;
  const int bc = blockIdx.x;
  const int b = bc >> 6;
  const int c = bc & (NCHUNK - 1);
  const int t0 = c * SS;
  const size_t tileBase = ((size_t)b * LL + t0) * DD;
  float* stc = states + ((size_t)b * NCHUNK + c) * (size_t)STATE;
  unsigned short* pqT = phiQg + (size_t)bc * 4096;
  unsigned short* pkT = phiKg + (size_t)bc * 4096;

  stage_hl(P0, P1, proj, tid);
  stage_hl(X0, X1, Qg + tileBase, tid);
  stage_hl(Y0, Y1, Kg + tileBase, tid);
  stage_vhalf(F, Vg + tileBase, tid);
  float scq[4], sck[4];
#pragma unroll
  for (int ri = 0; ri < 4; ++ri) {
    const int trow = w * 16 + ((lane & 48) >> 2) + ri;
    scq[ri] = ws[t0 + trow] * 0.125f;        // * 1/sqrt(64)
    sck[ri] = ws[LL + t0 + trow] * 0.125f;
  }
  __syncthreads();  // bar0

  {  // phiQ: overwrite X0 rows (wave-local A-operand rows -> safe in place)
    f32x4 acc[4] = {};
    logits3(X0, X1, P0, P1, w, acc);
    phi_store_row(X0, acc, scq, w);
  }
  {  // phiK -> row image (fresh) + col image (fresh)
    f32x4 acc[4] = {};
    logits3(Y0, Y1, P0, P1, w, acc);
    phi_store_row(PHIr, acc, sck, w);
    phi_store_col(PHIc, acc, sck, w);
  }
  __syncthreads();  // bar1

  vtrans_half(Y0, Y1, F, tid, 0);  // K dead -> VT half 0
  {  // coalesced image copies to global
    const int o = tid * 16;
    *(u16x8*)(pqT + o)     = *(const u16x8*)(X0 + o);
    *(u16x8*)(pqT + o + 8) = *(const u16x8*)(X0 + o + 8);
    *(u16x8*)(pkT + o)     = *(const u16x8*)(PHIr + o);
    *(u16x8*)(pkT + o + 8) = *(const u16x8*)(PHIr + o + 8);
  }
  {  // N[m] from quantized phiK (col image: contiguous in t)
    const int m = tid >> 2, q = tid & 3;
    float s = 0.f;
#pragma unroll
    for (int p = 0; p < 2; ++p) {
      const int tt = q * 16 + p * 8;
      const u16x8 vv = *(const u16x8*)(PHIc + m * 64 + (tt ^ ((m & 7) << 3)));
#pragma unroll
      for (int i = 0; i < 8; ++i) s += bf2f(vv[i]);
    }
    s += __shfl_xor(s, 1);
    s += __shfl_xor(s, 2);
    if (q == 0) stc[4096 + m] = s;
  }
  __syncthreads();  // bar2 (F consumed by vtrans0)
  stage_vhalf(F, Vg + tileBase + 32 * 64, tid);
  __syncthreads();  // bar3
  vtrans_half(Y0, Y1, F, tid, 1);
  __syncthreads();  // bar4

  // KVT[d][m] = sum_t VT[d][t] * phiK[t][m]   (V hi/lo split)
  {
    s16x8 avh[2], avl[2];
#pragma unroll
    for (int ks = 0; ks < 2; ++ks) {
      avh[ks] = ld_frag(Y0, w * 16, ks);
      avl[ks] = ld_frag(Y1, w * 16, ks);
    }
    f32x4 acc[4] = {};
#pragma unroll
    for (int ct = 0; ct < 4; ++ct) {
#pragma unroll
      for (int ks = 0; ks < 2; ++ks) {
        const s16x8 bp = ld_frag(PHIc, ct * 16, ks);
        acc[ct] = MFMA(avh[ks], bp, acc[ct]);
        acc[ct] = MFMA(avl[ks], bp, acc[ct]);
      }
    }
#pragma unroll
    for (int ri = 0; ri < 4; ++ri) {
      const int d = w * 16 + ((lane & 48) >> 2) + ri;
#pragma unroll
      for (int ct = 0; ct < 4; ++ct) {
        stc[d * 64 + ct * 16 + (lane & 15)] = acc[ct][ri];
      }
    }
  }
}

// ---------------- K3: exclusive prefix over chunks (2-pass) ----------------
__global__ __launch_bounds__(256) void k_prefix1(const float* __restrict__ states,
                                                 float* __restrict__ tmp) {
  const int e = blockIdx.x * 256 + threadIdx.x;
  if (e >= BB * 8 * STATE) return;
  const int b = e / (8 * STATE);
  const int r = e % (8 * STATE);
  const int g = r / STATE;
  const int el = r % STATE;
  const float* p = states + ((size_t)b * NCHUNK + g * 8) * STATE + el;
  float s = 0.f;
#pragma unroll
  for (int i = 0; i < 8; ++i) s += p[(size_t)i * STATE];
  tmp[((size_t)b * 8 + g) * STATE + el] = s;
}

__global__ __launch_bounds__(256) void k_prefix2(float* __restrict__ states,
                                                 const float* __restrict__ tmp) {
  const int e = blockIdx.x * 256 + threadIdx.x;
  if (e >= BB * 8 * STATE) return;
  const int b = e / (8 * STATE);
  const int r = e % (8 * STATE);
  const int g = r / STATE;
  const int el = r % STATE;
  float run = 0.f;
  for (int g2 = 0; g2 < g; ++g2) run += tmp[((size_t)b * 8 + g2) * STATE + el];
  float* p = states + ((size_t)b * NCHUNK + g * 8) * STATE + el;
#pragma unroll
  for (int i = 0; i < 8; ++i) {
    const float v = p[(size_t)i * STATE];
    p[(size_t)i * STATE] = run;
    run += v;
  }
}

// ---------------- K4: outputs (no logits, no exp — phi read from ws) ----------------
__global__ __launch_bounds__(256) void k_out(const float* __restrict__ Vg,
                                             const unsigned short* __restrict__ phiQg,
                                             const unsigned short* __restrict__ phiKg,
                                             const float* __restrict__ states,
                                             float* __restrict__ out) {
  __shared__ unsigned short PQ[4096];            // phiQ image [t][m]
  __shared__ unsigned short PK[4096];            // phiK image [j][m]
  __shared__ unsigned short E[4096];             // masked quantized A [t][j]
  __shared__ unsigned short KV0[4096], KV1[4096];// KV prefix hi/lo [d][m]
  __shared__ unsigned short VT0[4096], VT1[4096];// V^T hi/lo [d][t]
  __shared__ float F[4096];                      // V f32 full tile
  const int tid = threadIdx.x;
  const int lane = tid & 63;
  const int w = tid >> 6;
  const int bc = blockIdx.x;
  const int b = bc >> 6;
  const int c = bc & (NCHUNK - 1);
  const int t0 = c * SS;
  const size_t tileBase = ((size_t)b * LL + t0) * DD;
  const float* st = states + ((size_t)b * NCHUNK + c) * (size_t)STATE;
  const unsigned short* pqT = phiQg + (size_t)bc * 4096;
  const unsigned short* pkT = phiKg + (size_t)bc * 4096;

  {  // phi image copies (coalesced)
    const int o = tid * 16;
    *(u16x8*)(PQ + o)     = *(const u16x8*)(pqT + o);
    *(u16x8*)(PQ + o + 8) = *(const u16x8*)(pqT + o + 8);
    *(u16x8*)(PK + o)     = *(const u16x8*)(pkT + o);
    *(u16x8*)(PK + o + 8) = *(const u16x8*)(pkT + o + 8);
  }
  stage_hl(KV0, KV1, st, tid);
  stage_vfull(F, Vg + tileBase, tid);
  __syncthreads();  // bar0

  vtrans_half(VT0, VT1, F, tid, 0);
  vtrans_half(VT0, VT1, F + 32 * 64, tid, 1);

  // A = phiQ . phiK^T (wave row-tile), masked + quantized -> E (wave-local rows);
  // row-sums rsI from quantized A.
  float rsI[4];
  s16x8 aq[2];
#pragma unroll
  for (int ks = 0; ks < 2; ++ks) aq[ks] = ld_frag(PQ, w * 16, ks);
  {
    f32x4 accA[4] = {};
#pragma unroll
    for (int ct = 0; ct < 4; ++ct) {
#pragma unroll
      for (int ks = 0; ks < 2; ++ks) {
        accA[ct] = MFMA(aq[ks], ld_frag(PK, ct * 16, ks), accA[ct]);
      }
    }
#pragma unroll
    for (int ri = 0; ri < 4; ++ri) {
      const int t = w * 16 + ((lane & 48) >> 2) + ri;
      float part = 0.f;
#pragma unroll
      for (int ct = 0; ct < 4; ++ct) {
        const int j = ct * 16 + (lane & 15);
        const float a = (j <= t) ? accA[ct][ri] : 0.f;
        const unsigned short ah = f2bf(a);
        part += bf2f(ah);
        E[t * 64 + (j ^ ((t & 7) << 3))] = ah;
      }
#pragma unroll
      for (int off = 1; off < 16; off <<= 1) part += __shfl_xor(part, off);
      rsI[ri] = part;
    }
  }
  __syncthreads();  // bar1 (VT complete; E wave-local so no extra barrier needed)

  // acc = A.(VTh+VTl)^T + phiQ.(KVh+KVl);  r = rsI + phiQ.Npref
  {
    s16x8 aA[2];
#pragma unroll
    for (int ks = 0; ks < 2; ++ks) aA[ks] = ld_frag(E, w * 16, ks);
    f32x4 acc[4] = {};
#pragma unroll
    for (int ct = 0; ct < 4; ++ct) {
#pragma unroll
      for (int ks = 0; ks < 2; ++ks) {
        acc[ct] = MFMA(aA[ks], ld_frag(VT0, ct * 16, ks), acc[ct]);
        acc[ct] = MFMA(aA[ks], ld_frag(VT1, ct * 16, ks), acc[ct]);
        acc[ct] = MFMA(aq[ks], ld_frag(KV0, ct * 16, ks), acc[ct]);
        acc[ct] = MFMA(aq[ks], ld_frag(KV1, ct * 16, ks), acc[ct]);
      }
    }
    // prefix part of denominator: dot(phiQ[t,:], Npref) from the quantized phiQ frags
    float rsp = 0.f;
    const float* Np = st + 4096;
#pragma unroll
    for (int ks = 0; ks < 2; ++ks) {
      const int m0 = ks * 32 + ((lane & 48) >> 1);
      const float4 n0 = *(const float4*)(Np + m0);
      const float4 n1 = *(const float4*)(Np + m0 + 4);
      const float nn[8] = {n0.x, n0.y, n0.z, n0.w, n1.x, n1.y, n1.z, n1.w};
#pragma unroll
      for (int i = 0; i < 8; ++i) rsp += bf2f((unsigned short)aq[ks][i]) * nn[i];
    }
    rsp += __shfl_xor(rsp, 16);
    rsp += __shfl_xor(rsp, 32);
    // rsp holds r_prefix for row t = w*16 + (lane&15); redistribute to C-row layout
#pragma unroll
    for (int ri = 0; ri < 4; ++ri) {
      const float r = rsI[ri] + __shfl(rsp, ((lane & 48) >> 2) + ri);
      const float inv = 1.f / (r + copysignf(1e-6f, r));
      const int t = w * 16 + ((lane & 48) >> 2) + ri;
#pragma unroll
      for (int ct = 0; ct < 4; ++ct) {
        out[tileBase + t * 64 + ct * 16 + (lane & 15)] = acc[ct][ri] * inv;
      }
    }
  }
}

extern "C" void kernel_launch(void* const* d_in, const int* in_sizes, int n_in,
                              void* d_out, int out_size, void* d_ws, size_t ws_size,
                              hipStream_t stream) {
  (void)in_sizes; (void)n_in; (void)out_size; (void)ws_size;
  const float* Q    = (const float*)d_in[0];
  const float* K    = (const float*)d_in[1];
  const float* V    = (const float*)d_in[2];
  const float* proj = (const float*)d_in[4];  // d_in[3] = sent_embed_slice (unused)
  float* out = (float*)d_out;
  float* ws  = (float*)d_ws;
  float* states = ws + 2 * LL;                                  // B*64*4160 f
  const size_t statesFloats = (size_t)BB * NCHUNK * STATE;
  float* tmp = states + statesFloats;                           // B*8*4160 f
  const size_t tmpFloats = (size_t)BB * 8 * STATE;
  unsigned short* phiQg = (unsigned short*)(tmp + tmpFloats);   // 512*4096 u16
  unsigned short* phiKg = phiQg + (size_t)BB * NCHUNK * 4096;

  hipLaunchKernelGGL(k_scales, dim3(LL / 4), dim3(256), 0, stream, Q, K, ws);
  hipLaunchKernelGGL(k_phi_sums, dim3(BB * NCHUNK), dim3(256), 0, stream,
                     Q, K, V, proj, ws, states, phiQg, phiKg);
  hipLaunchKernelGGL(k_prefix1, dim3((BB * 8 * STATE + 255) / 256), dim3(256), 0, stream, states, tmp);
  hipLaunchKernelGGL(k_prefix2, dim3((BB * 8 * STATE + 255) / 256), dim3(256), 0, stream, states, tmp);
  hipLaunchKernelGGL(k_out, dim3(BB * NCHUNK), dim3(256), 0, stream,
                     V, phiQg, phiKg, states, out);
}